// Round 11
// baseline (355.289 us; speedup 1.0000x reference)
//
#include <hip/hip_runtime.h>
#include <hip/hip_bf16.h>

#define LEN 128
#define NB 32
#define NC 16
#define NU 16
#define NK 5
#define KC 80          // (k,c) pairs
#define KCP 96         // padded K for stage2

typedef unsigned int uint32;
typedef unsigned short ushort16;
typedef __attribute__((ext_vector_type(8))) short bf16x8;
typedef __attribute__((ext_vector_type(4))) float f32x4;

#define MFMA(a, b, c) __builtin_amdgcn_mfma_f32_16x16x32_bf16(a, b, c, 0, 0, 0)

// XOR swizzle of the 16B-unit index within a 64-dword row (16 units).
#define SIG(r) (((r) & 15) ^ (((r) >> 3) & 15))

static __device__ inline ushort16 f2bf(float f) {
    union { float f; uint32 u; } v; v.f = f;
    uint32 u = v.u;
    uint32 r = (u + 0x7fffu + ((u >> 16) & 1u)) >> 16;   // RNE
    return (ushort16)r;
}
static __device__ inline uint32 pkbf(float a, float b) {   // low=a, high=b (verified r0-r10)
    return (uint32)f2bf(a) | ((uint32)f2bf(b) << 16);
}
static __device__ inline bf16x8 frag16(const void* p) {    // 16B-aligned
    return *(const bf16x8*)p;
}

// ---------------- kprep: blocks 0..511 = x->xF transpose (+ t1 k=0 identity rows);
//                         blocks 512..1181 = const operands ----------------
__global__ __launch_bounds__(256) void kprep(const float* __restrict__ x,
                                             const float* __restrict__ coefs,
                                             const float* __restrict__ cheb1,
                                             const float* __restrict__ cheb2,
                                             ushort16* __restrict__ xF,
                                             ushort16* __restrict__ cheb1F,
                                             ushort16* __restrict__ cheb2F,
                                             ushort16* __restrict__ coefF,
                                             ushort16* __restrict__ t1, int ident) {
    __shared__ __align__(16) uint32 Xs[128 * 64];   // [w][h-pair units swizzled]
    const int blk = blockIdx.x, tid = threadIdx.x;
    if (blk < 512) {
        const int bc = blk;
        const float* xp = x + (size_t)bc * (LEN * LEN);
        {
            int w = tid & 127, hg = tid >> 7;
            #pragma unroll
            for (int uu = 0; uu < 8; ++uu) {
                int u = hg * 8 + uu;
                uint4 d;
                uint32* dp = (uint32*)&d;
                #pragma unroll
                for (int t = 0; t < 4; ++t) {
                    int h2 = u * 4 + t;
                    dp[t] = pkbf(xp[(2 * h2) * LEN + w], xp[(2 * h2 + 1) * LEN + w]);
                }
                *(uint4*)(Xs + w * 64 + ((u ^ SIG(w)) << 2)) = d;
            }
        }
        // t1 k=0 identity rows: t1[b][p][kc=c][w] = bf16(x[b][c][p][w])
        if (ident) {
            const int b = bc >> 4, c = bc & 15;
            int p = tid >> 1, half = tid & 1;
            const float4* src = (const float4*)(xp + p * LEN + half * 64);
            ushort16* dst = t1 + ((size_t)(b * LEN + p) * KC + c) * LEN + half * 64;
            #pragma unroll
            for (int i = 0; i < 16; ++i) {
                float4 v = src[i];
                uint2 d;
                d.x = pkbf(v.x, v.y);
                d.y = pkbf(v.z, v.w);
                *(uint2*)(dst + i * 4) = d;
            }
        }
        __syncthreads();
        ushort16* dst = xF + (size_t)bc * 16384;
        #pragma unroll
        for (int i = 0; i < 8; ++i) {
            int n = tid + i * 256;               // 0..2047 fragment-units of 16B
            int lane = n & 63, fk = n >> 6;      // fk = mt*4+ks
            int wrow = (fk >> 2) * 16 + (lane & 15);
            int u = (fk & 3) * 4 + (lane >> 4);
            uint4 v = *(const uint4*)(Xs + wrow * 64 + ((u ^ SIG(wrow)) << 2));
            *(uint4*)(dst + (size_t)n * 8) = v;
        }
    } else {
        int i = (blk - 512) * 256 + tid;         // 0..171519
        if (i < 81920) {
            int j = i & 7, lane = (i >> 3) & 63, ks = (i >> 9) & 3, nt = i >> 11;
            int kp = nt * 16 + (lane & 15);
            int k = kp >> 7, p = kp & 127;
            int h = ks * 32 + ((lane >> 4) << 3) + j;
            cheb1F[i] = f2bf(cheb1[(k * LEN + h) * LEN + p]);
        } else if (i < 163840) {
            int i2 = i - 81920;
            int j = i2 & 7, lane = (i2 >> 3) & 63, t = i2 >> 9;
            int ks = t % 20, nt = t / 20;
            int q = nt * 16 + (lane & 15);
            int lw = ks * 32 + ((lane >> 4) << 3) + j;
            int l = lw >> 7, w = lw & 127;
            cheb2F[i2] = f2bf(cheb2[(l * LEN + w) * LEN + q]);
        } else {
            int i3 = i - 163840;
            int j = i3 & 7, lane = (i3 >> 3) & 63, t = i3 >> 9;
            int ks = t % 3, nt = t / 3;
            int lu = nt * 16 + (lane & 15);
            int l = lu >> 4, u = lu & 15;
            int kc = ks * 32 + ((lane >> 4) << 3) + j;
            int k = kc >> 4, c = kc & 15;
            coefF[i3] = (kc < KC) ? f2bf(coefs[((k * NK + l) * NC + c) * NU + u]) : (ushort16)0;
        }
    }
}

// ---------------- k1: t1[bl][p][kc][w] = sum_h cheb1[k][h][p]*x[b][c][h][w]
// k=0 handled by kprep (T_0 = I identity). GEMM covers kp in [128,640):
// grid (c, bl, z 0..7), 64 kp/seg. Verified structure: LDS-free GEMM,
// wave-contiguous 1KB fragment reads, 16KB LDS bounce for coalesced stores.
__global__ __launch_bounds__(256, 5) void k1_mfma(const ushort16* __restrict__ xF,
                                                  const ushort16* __restrict__ cheb1F,
                                                  const float* __restrict__ x,
                                                  ushort16* __restrict__ t1, int b0, int ident) {
    __shared__ __align__(16) uint32 Bs[64 * 64];   // bounce: 64 kp-rows x 128 w bf16, swizzled
    const int c = blockIdx.x, bl = blockIdx.y, z = blockIdx.z;
    const int b = b0 + bl;
    const int tid = threadIdx.x;
    const int lane = tid & 63, wm = tid >> 6;      // wave = m-quarter
    const int m16 = lane & 15, g = lane >> 4;

    // fallback identity copy (only when kprep couldn't do it: chunk != NB)
    if (!ident && z == 0) {
        const float* xp = x + (size_t)(b * NC + c) * (LEN * LEN);
        int p = tid >> 1, half = tid & 1;
        const float4* src = (const float4*)(xp + p * LEN + half * 64);
        ushort16* dst = t1 + ((size_t)(bl * LEN + p) * KC + c) * LEN + half * 64;
        #pragma unroll
        for (int i = 0; i < 16; ++i) {
            float4 v = src[i];
            uint2 d;
            d.x = pkbf(v.x, v.y);
            d.y = pkbf(v.z, v.w);
            *(uint2*)(dst + i * 4) = d;
        }
    }

    const ushort16* xFb = xF + ((size_t)(b * NC + c)) * 16384;

    f32x4 acc[2][4];
    #pragma unroll
    for (int mi = 0; mi < 2; ++mi)
        #pragma unroll
        for (int ni = 0; ni < 4; ++ni) acc[mi][ni] = (f32x4)0.f;

    #pragma unroll
    for (int ks = 0; ks < 4; ++ks) {
        bf16x8 Af[2], Bf[4];
        #pragma unroll
        for (int mi = 0; mi < 2; ++mi) {
            int mt = wm * 2 + mi;
            Af[mi] = frag16(xFb + ((size_t)(mt * 4 + ks) * 64 + lane) * 8);
        }
        #pragma unroll
        for (int ni = 0; ni < 4; ++ni) {
            int nt = 8 + z * 4 + ni;
            Bf[ni] = frag16(cheb1F + ((size_t)(nt * 4 + ks) * 64 + lane) * 8);
        }
        #pragma unroll
        for (int mi = 0; mi < 2; ++mi)
            #pragma unroll
            for (int ni = 0; ni < 4; ++ni)
                acc[mi][ni] = MFMA(Af[mi], Bf[ni], acc[mi][ni]);
    }

    // bounce: D element (m = w = wm*32+mi*16+g*4+r, n = rr = ni*16+m16)
    #pragma unroll
    for (int ni = 0; ni < 4; ++ni)
        #pragma unroll
        for (int mi = 0; mi < 2; ++mi) {
            int rr = ni * 16 + m16;
            int wu = wm * 32 + mi * 16 + g * 4;       // ushort col (w)
            uint2 d;
            d.x = pkbf(acc[mi][ni][0], acc[mi][ni][1]);
            d.y = pkbf(acc[mi][ni][2], acc[mi][ni][3]);
            int u = wu >> 3;
            *(uint2*)(Bs + rr * 64 + ((u ^ SIG(rr)) << 2) + ((wu >> 1) & 3)) = d;
        }
    __syncthreads();

    // read-out + coalesced store (256B runs); kp = 128 + z*64 + rr
    #pragma unroll
    for (int i = 0; i < 4; ++i) {
        int n = tid + i * 256;                 // 0..1023
        int rr = n >> 4, wsg = n & 15;
        uint4 v = *(const uint4*)(Bs + rr * 64 + ((wsg ^ SIG(rr)) << 2));
        int kp = 128 + z * 64 + rr;
        int k = kp >> 7, p = kp & 127;
        *(uint4*)(t1 + ((size_t)((bl * LEN + p) * KC + k * NC + c)) * LEN + wsg * 8) = v;
    }
}

// ---------------- k2: per (pblk, bl) block: 4 consecutive p-slices in a loop.
// Grid 32 x cb = 1024 blocks -> exactly 4 resident blocks/CU (32KB LDS), no
// dispatch churn. Stage-3 B fragments (cheb2F, 32 frags = 128 VGPR) loaded ONCE
// per block and held in registers across all 4 p (cuts cheb2F L2 traffic 4x).
// t1(p+1) prefetched into regs under stage2/3 compute (T14).
// stage2: s[w][lu] = Ts[w][kc] x coefF (K=96 zero-padded); stage3: ks 4..19
// (l=0 identity skipped, added in epilogue).
__global__ __launch_bounds__(256, 4) void k2_mfma(const ushort16* __restrict__ t1,
                                                  const ushort16* __restrict__ coefF,
                                                  const ushort16* __restrict__ cheb2F,
                                                  float* __restrict__ out, int b0) {
    __shared__ __align__(16) uint32 sm[128 * 64];   // 32KB: Ts [w][kc units swz]; A3 (16x648 ush) aliases
    const int pblk = blockIdx.x, bl = blockIdx.y, b = b0 + bl;
    const int tid = threadIdx.x;
    const int lane = tid & 63, wave = tid >> 6;
    const int n16 = lane & 15, g = lane >> 4;

    // ---- stage-3 B operand: wave's 32 q x ks 4..19, held in regs for all 4 p
    bf16x8 B3[32];
    #pragma unroll
    for (int nt = 0; nt < 2; ++nt)
        #pragma unroll
        for (int ks = 4; ks < 20; ++ks)
            B3[nt * 16 + ks - 4] =
                frag16(cheb2F + ((size_t)((wave * 2 + nt) * 20 + ks) * 64 + lane) * 8);

    const uint32* t1base = (const uint32*)(t1 + (size_t)(bl * LEN + pblk * 4) * (KC * LEN));

    // ---- load t1(p0)
    uint4 Av[3], Bv[3];
    #pragma unroll
    for (int i = 0; i < 3; ++i) {
        int it = tid + i * 256;              // 0..639 active
        if (it < 640) {
            int a2 = it >> 4, wq = it & 15;  // a2 = kc-pair 0..39
            const uint32* src = t1base + a2 * 128 + wq * 4;
            Av[i] = *(const uint4*)(src);
            Bv[i] = *(const uint4*)(src + 64);
        }
    }

    for (int pi = 0; pi < 4; ++pi) {
        const int p = pblk * 4 + pi;
        if (pi) __syncthreads();             // prev iteration's A3 reads done

        // re-zero K-pad (units 10,11; A3 clobbered them last iteration)
        #pragma unroll
        for (int i = 0; i < 4; ++i) {
            int idx = tid + i * 256;         // 0..1023
            int row = idx >> 3, d = idx & 7;
            int u = 10 + (d >> 2);
            sm[row * 64 + ((u ^ SIG(row)) << 2) + (d & 3)] = 0;
        }
        // write Ts(p): transpose kc-pairs into swizzled rows
        #pragma unroll
        for (int i = 0; i < 3; ++i) {
            int it = tid + i * 256;
            if (it < 640) {
                int a2 = it >> 4, wq = it & 15;
                const uint32* av = (const uint32*)&Av[i];
                const uint32* bv = (const uint32*)&Bv[i];
                int u = a2 >> 2, lo = a2 & 3;
                #pragma unroll
                for (int j = 0; j < 4; ++j) {
                    int r0 = wq * 8 + 2 * j, r1 = r0 + 1;
                    sm[r0 * 64 + ((u ^ SIG(r0)) << 2) + lo] = (av[j] & 0xffffu) | (bv[j] << 16);
                    sm[r1 * 64 + ((u ^ SIG(r1)) << 2) + lo] = (av[j] >> 16) | (bv[j] & 0xffff0000u);
                }
            }
        }
        __syncthreads();

        // prefetch t1(p+1): latency hides under stage2 + A3 + stage3
        if (pi < 3) {
            const uint32* nsrc = t1base + (size_t)(pi + 1) * 5120;
            #pragma unroll
            for (int i = 0; i < 3; ++i) {
                int it = tid + i * 256;
                if (it < 640) {
                    int a2 = it >> 4, wq = it & 15;
                    const uint32* src = nsrc + a2 * 128 + wq * 4;
                    Av[i] = *(const uint4*)(src);
                    Bv[i] = *(const uint4*)(src + 64);
                }
            }
        }

        // ---- stage2: rows w = wave*32 + mi*16 + n16
        f32x4 acc[2][5];
        #pragma unroll
        for (int mi = 0; mi < 2; ++mi)
            #pragma unroll
            for (int ni = 0; ni < 5; ++ni) acc[mi][ni] = (f32x4)0.f;

        #pragma unroll
        for (int ks = 0; ks < 3; ++ks) {
            bf16x8 Af[2], Bf[5];
            #pragma unroll
            for (int mi = 0; mi < 2; ++mi) {
                int row = wave * 32 + mi * 16 + n16;
                Af[mi] = frag16(sm + row * 64 + (((ks * 4 + g) ^ SIG(row)) << 2));
            }
            #pragma unroll
            for (int ni = 0; ni < 5; ++ni)
                Bf[ni] = frag16(coefF + ((size_t)(ni * 3 + ks) * 64 + lane) * 8);
            #pragma unroll
            for (int mi = 0; mi < 2; ++mi)
                #pragma unroll
                for (int ni = 0; ni < 5; ++ni)
                    acc[mi][ni] = MFMA(Af[mi], Bf[ni], acc[mi][ni]);
        }
        __syncthreads();   // Ts reads done; A3 may overwrite

        // s -> A3: row u = n16 (16 rows, stride 648 ushort), col l*128+w
        {
            ushort16* A3 = (ushort16*)sm;
            #pragma unroll
            for (int mi = 0; mi < 2; ++mi)
                #pragma unroll
                for (int ni = 0; ni < 5; ++ni) {
                    int wcol = wave * 32 + mi * 16 + g * 4;
                    uint2 d;
                    d.x = pkbf(acc[mi][ni][0], acc[mi][ni][1]);
                    d.y = pkbf(acc[mi][ni][2], acc[mi][ni][3]);
                    *(uint2*)(A3 + n16 * 648 + ni * 128 + wcol) = d;
                }
        }
        __syncthreads();

        // ---- stage3: M=16 (u), wave owns 32 q; B from registers. ks 4..19.
        const ushort16* A3r = (const ushort16*)sm;
        f32x4 c3[2];
        c3[0] = (f32x4)0.f; c3[1] = (f32x4)0.f;
        #pragma unroll
        for (int ks = 4; ks < 20; ++ks) {
            bf16x8 Aa = frag16(A3r + n16 * 648 + ks * 32 + g * 8);
            c3[0] = MFMA(Aa, B3[ks - 4], c3[0]);
            c3[1] = MFMA(Aa, B3[16 + ks - 4], c3[1]);
        }

        #pragma unroll
        for (int nt = 0; nt < 2; ++nt)
            #pragma unroll
            for (int r = 0; r < 4; ++r) {
                int u = g * 4 + r;
                int q = wave * 32 + nt * 16 + n16;
                // l=0 identity contribution: + s[u][w=q] (bf16 in A3 col q)
                uint32 bf = ((uint32)A3r[u * 648 + q]) << 16;
                float l0 = __uint_as_float(bf);
                out[(((size_t)(b * NU + u)) * LEN + p) * LEN + q] = c3[nt][r] + l0;
            }
    }
}

extern "C" void kernel_launch(void* const* d_in, const int* in_sizes, int n_in,
                              void* d_out, int out_size, void* d_ws, size_t ws_size,
                              hipStream_t stream) {
    const float* x     = (const float*)d_in[0];
    const float* coefs = (const float*)d_in[1];
    const float* cheb1 = (const float*)d_in[2];
    const float* cheb2 = (const float*)d_in[3];
    float* out = (float*)d_out;

    const size_t xF_bytes  = (size_t)NB * NC * 16384 * sizeof(ushort16);   // 16.8 MB
    const size_t aux_bytes = 163840 + 163840 + 15360;                      // cheb1F + cheb2F + coefF
    size_t off = (ws_size - aux_bytes - xF_bytes) & ~(size_t)255;
    ushort16* cheb1F = (ushort16*)((char*)d_ws + off);
    ushort16* cheb2F = cheb1F + 81920;
    ushort16* coefF  = cheb2F + 81920;
    ushort16* xF     = coefF + 7680;
    ushort16* t1 = (ushort16*)d_ws;

    const size_t per_b = (size_t)LEN * KC * LEN * sizeof(ushort16);        // 2.62 MB
    int chunk = (int)(off / per_b);
    if (chunk < 1) chunk = 1;
    if (chunk > NB) chunk = NB;
    const int ident = (chunk == NB) ? 1 : 0;    // kprep can write t1 k=0 rows directly

    hipLaunchKernelGGL(kprep, dim3(1182), dim3(256), 0, stream,
                       x, coefs, cheb1, cheb2, xF, cheb1F, cheb2F, coefF, t1, ident);
    for (int b0 = 0; b0 < NB; b0 += chunk) {
        int cb = (NB - b0 < chunk) ? (NB - b0) : chunk;
        hipLaunchKernelGGL(k1_mfma, dim3(NC, cb, 8), dim3(256), 0, stream,
                           xF, cheb1F, x, t1, b0, ident);
        hipLaunchKernelGGL(k2_mfma, dim3(32, cb), dim3(256), 0, stream,
                           t1, coefF, cheb2F, out, b0);
    }
}

// Round 12
// 155.069 us; speedup vs baseline: 2.2912x; 2.2912x over previous
//
#include <hip/hip_runtime.h>
#include <hip/hip_bf16.h>

#define LEN 128
#define NB 32
#define NC 16
#define NU 16
#define NK 5
#define KC 80          // (k,c) pairs
#define KCP 96         // padded K for stage2

typedef unsigned int uint32;
typedef unsigned short ushort16;
typedef __attribute__((ext_vector_type(8))) short bf16x8;
typedef __attribute__((ext_vector_type(4))) float f32x4;

#define MFMA(a, b, c) __builtin_amdgcn_mfma_f32_16x16x32_bf16(a, b, c, 0, 0, 0)

// XOR swizzle of the 16B-unit index within a 64-dword row (16 units).
#define SIG(r) (((r) & 15) ^ (((r) >> 3) & 15))

static __device__ inline ushort16 f2bf(float f) {
    union { float f; uint32 u; } v; v.f = f;
    uint32 u = v.u;
    uint32 r = (u + 0x7fffu + ((u >> 16) & 1u)) >> 16;   // RNE
    return (ushort16)r;
}
static __device__ inline uint32 pkbf(float a, float b) {   // low=a, high=b (verified r0-r10)
    return (uint32)f2bf(a) | ((uint32)f2bf(b) << 16);
}
static __device__ inline bf16x8 frag16(const void* p) {    // 16B-aligned
    return *(const bf16x8*)p;
}

// ---------------- kprep: blocks 0..511 = x->xF transpose; 512..1181 = const operands ----------------
__global__ __launch_bounds__(256) void kprep(const float* __restrict__ x,
                                             const float* __restrict__ coefs,
                                             const float* __restrict__ cheb1,
                                             const float* __restrict__ cheb2,
                                             ushort16* __restrict__ xF,
                                             ushort16* __restrict__ cheb1F,
                                             ushort16* __restrict__ cheb2F,
                                             ushort16* __restrict__ coefF) {
    __shared__ __align__(16) uint32 Xs[128 * 64];   // [w][h-pair units swizzled]
    const int blk = blockIdx.x, tid = threadIdx.x;
    if (blk < 512) {
        const int bc = blk;
        const float* xp = x + (size_t)bc * (LEN * LEN);
        {
            int w = tid & 127, hg = tid >> 7;
            #pragma unroll
            for (int uu = 0; uu < 8; ++uu) {
                int u = hg * 8 + uu;
                uint4 d;
                uint32* dp = (uint32*)&d;
                #pragma unroll
                for (int t = 0; t < 4; ++t) {
                    int h2 = u * 4 + t;
                    dp[t] = pkbf(xp[(2 * h2) * LEN + w], xp[(2 * h2 + 1) * LEN + w]);
                }
                *(uint4*)(Xs + w * 64 + ((u ^ SIG(w)) << 2)) = d;
            }
        }
        __syncthreads();
        ushort16* dst = xF + (size_t)bc * 16384;
        #pragma unroll
        for (int i = 0; i < 8; ++i) {
            int n = tid + i * 256;               // 0..2047 fragment-units of 16B
            int lane = n & 63, fk = n >> 6;      // fk = mt*4+ks
            int wrow = (fk >> 2) * 16 + (lane & 15);
            int u = (fk & 3) * 4 + (lane >> 4);
            uint4 v = *(const uint4*)(Xs + wrow * 64 + ((u ^ SIG(wrow)) << 2));
            *(uint4*)(dst + (size_t)n * 8) = v;
        }
    } else {
        int i = (blk - 512) * 256 + tid;         // 0..171519
        if (i < 81920) {
            int j = i & 7, lane = (i >> 3) & 63, ks = (i >> 9) & 3, nt = i >> 11;
            int kp = nt * 16 + (lane & 15);
            int k = kp >> 7, p = kp & 127;
            int h = ks * 32 + ((lane >> 4) << 3) + j;
            cheb1F[i] = f2bf(cheb1[(k * LEN + h) * LEN + p]);
        } else if (i < 163840) {
            int i2 = i - 81920;
            int j = i2 & 7, lane = (i2 >> 3) & 63, t = i2 >> 9;
            int ks = t % 20, nt = t / 20;
            int q = nt * 16 + (lane & 15);
            int lw = ks * 32 + ((lane >> 4) << 3) + j;
            int l = lw >> 7, w = lw & 127;
            cheb2F[i2] = f2bf(cheb2[(l * LEN + w) * LEN + q]);
        } else {
            int i3 = i - 163840;
            int j = i3 & 7, lane = (i3 >> 3) & 63, t = i3 >> 9;
            int ks = t % 3, nt = t / 3;
            int lu = nt * 16 + (lane & 15);
            int l = lu >> 4, u = lu & 15;
            int kc = ks * 32 + ((lane >> 4) << 3) + j;
            int k = kc >> 4, c = kc & 15;
            coefF[i3] = (kc < KC) ? f2bf(coefs[((k * NK + l) * NC + c) * NU + u]) : (ushort16)0;
        }
    }
}

// ---------------- k1: t1[bl][p][kc][w] = sum_h cheb1[k][h][p]*x[b][c][h][w]
// T_0 = I  =>  t1[p][k=0][c][w] = bf16(x[b][c][p][w]) is a direct copy (done by
// z==0 blocks). GEMM covers kp in [128,640): grid (c, bl, z 0..7), 64 kp/seg.
// cheb1F segment (16KB) staged once in LDS (SIG-swizzled); waves 2x2 over
// (w-half, kp-half). Epilogue bounces through 16KB LDS for coalesced stores.
__global__ __launch_bounds__(256, 4) void k1_mfma(const ushort16* __restrict__ xF,
                                                  const ushort16* __restrict__ cheb1F,
                                                  const float* __restrict__ x,
                                                  ushort16* __restrict__ t1, int b0) {
    __shared__ __align__(16) uint32 Ls[64 * 64];   // cheb1F seg [kp_local][h-units swz]
    __shared__ __align__(16) uint32 Bs[64 * 64];   // bounce: 64 kp-rows x 128 w bf16, swz
    const int c = blockIdx.x, bl = blockIdx.y, z = blockIdx.z;
    const int b = b0 + bl;
    const int tid = threadIdx.x;
    const int lane = tid & 63, wave = tid >> 6;
    const int m16 = lane & 15, g = lane >> 4;
    const int wm = wave >> 1, wn = wave & 1;       // 2x2 wave grid

    // stage cheb1F segment -> Ls (swizzled); unit u=(nt,ks,lane)
    #pragma unroll
    for (int i = 0; i < 4; ++i) {
        int u = tid + i * 256;            // 0..1023
        int ln = u & 63, ks = (u >> 6) & 3, nt = u >> 8;
        uint4 v = *(const uint4*)(cheb1F + ((size_t)(((8 + z * 4 + nt) * 4 + ks) * 64 + ln)) * 8);
        int row = nt * 16 + (ln & 15), hu = ks * 4 + (ln >> 4);
        *(uint4*)(Ls + row * 64 + ((hu ^ SIG(row)) << 2)) = v;
    }

    // z==0: k=0 identity copy t1[p][kc=c][w] = bf16(x[b][c][p][w])
    if (z == 0) {
        const float* xp = x + (size_t)(b * NC + c) * (LEN * LEN);
        int p = tid >> 1, half = tid & 1;
        const float4* src = (const float4*)(xp + p * LEN + half * 64);
        ushort16* dst = t1 + ((size_t)(bl * LEN + p) * KC + c) * LEN + half * 64;
        #pragma unroll
        for (int i = 0; i < 16; ++i) {
            float4 v = src[i];
            uint2 d;
            d.x = pkbf(v.x, v.y);
            d.y = pkbf(v.z, v.w);
            *(uint2*)(dst + i * 4) = d;
        }
    }
    __syncthreads();

    const ushort16* xFb = xF + ((size_t)(b * NC + c)) * 16384;

    f32x4 acc[4][2];
    #pragma unroll
    for (int mi = 0; mi < 4; ++mi)
        #pragma unroll
        for (int ni = 0; ni < 2; ++ni) acc[mi][ni] = (f32x4)0.f;

    #pragma unroll
    for (int ks = 0; ks < 4; ++ks) {
        bf16x8 Af[4], Bf[2];
        #pragma unroll
        for (int mi = 0; mi < 4; ++mi) {
            int mt = wm * 4 + mi;
            Af[mi] = frag16(xFb + ((size_t)(mt * 4 + ks) * 64 + lane) * 8);
        }
        #pragma unroll
        for (int ni = 0; ni < 2; ++ni) {
            int row = (wn * 2 + ni) * 16 + m16;
            int hu = ks * 4 + g;
            Bf[ni] = frag16(Ls + row * 64 + ((hu ^ SIG(row)) << 2));
        }
        #pragma unroll
        for (int mi = 0; mi < 4; ++mi)
            #pragma unroll
            for (int ni = 0; ni < 2; ++ni)
                acc[mi][ni] = MFMA(Af[mi], Bf[ni], acc[mi][ni]);
    }

    // bounce: D element (m = w = (wm*4+mi)*16+g*4+r, n = kp_local = (wn*2+ni)*16+m16)
    #pragma unroll
    for (int ni = 0; ni < 2; ++ni)
        #pragma unroll
        for (int mi = 0; mi < 4; ++mi) {
            int rr = (wn * 2 + ni) * 16 + m16;
            int wu = (wm * 4 + mi) * 16 + g * 4;      // ushort col (w)
            uint2 d;
            d.x = pkbf(acc[mi][ni][0], acc[mi][ni][1]);
            d.y = pkbf(acc[mi][ni][2], acc[mi][ni][3]);
            int u = wu >> 3;
            *(uint2*)(Bs + rr * 64 + ((u ^ SIG(rr)) << 2) + ((wu >> 1) & 3)) = d;
        }
    __syncthreads();

    // read-out + coalesced store (256B runs); kp = 128 + z*64 + rr
    #pragma unroll
    for (int i = 0; i < 4; ++i) {
        int n = tid + i * 256;                 // 0..1023
        int rr = n >> 4, wsg = n & 15;
        uint4 v = *(const uint4*)(Bs + rr * 64 + ((wsg ^ SIG(rr)) << 2));
        int kp = 128 + z * 64 + rr;
        int k = kp >> 7, p = kp & 127;
        *(uint4*)(t1 + ((size_t)((bl * LEN + p) * KC + k * NC + c)) * LEN + wsg * 8) = v;
    }
}

// ---------------- k2: per (pblk, bl) block: 2 consecutive p-slices.
// __launch_bounds__(256,2) -> 256-VGPR cap: B3 (32 frags = 128 VGPR) held in
// registers across both p (halves cheb2F L2 traffic; stage3 has no mem ops).
// t1(p1) prefetched under stage2/3(p0) (T14). 32KB LDS; grid 64 x cb = 2048.
// stage2: s[w][lu] = Ts[w][kc] x coefF (K=96 zero-padded); stage3: ks 4..19
// (l=0 identity skipped, added in epilogue).
__global__ __launch_bounds__(256, 2) void k2_mfma(const ushort16* __restrict__ t1,
                                                  const ushort16* __restrict__ coefF,
                                                  const ushort16* __restrict__ cheb2F,
                                                  float* __restrict__ out, int b0) {
    __shared__ __align__(16) uint32 sm[128 * 64];   // 32KB: Ts [w][kc units swz]; A3 (16x648 ush) aliases
    const int pblk = blockIdx.x, bl = blockIdx.y, b = b0 + bl;
    const int tid = threadIdx.x;
    const int lane = tid & 63, wave = tid >> 6;
    const int n16 = lane & 15, g = lane >> 4;

    // stage-3 B operand: wave's 32 q x ks 4..19, in regs for both p (128 VGPR)
    bf16x8 B3[32];
    #pragma unroll
    for (int nt = 0; nt < 2; ++nt)
        #pragma unroll
        for (int ks = 4; ks < 20; ++ks)
            B3[nt * 16 + ks - 4] =
                frag16(cheb2F + ((size_t)((wave * 2 + nt) * 20 + ks) * 64 + lane) * 8);

    const uint32* t1base = (const uint32*)(t1 + (size_t)(bl * LEN + 2 * pblk) * (KC * LEN));

    // load t1(p0)
    uint4 Av[3], Bv[3];
    #pragma unroll
    for (int i = 0; i < 3; ++i) {
        int it = tid + i * 256;              // 0..639 active
        if (it < 640) {
            int a2 = it >> 4, wq = it & 15;  // a2 = kc-pair 0..39
            const uint32* src = t1base + a2 * 128 + wq * 4;
            Av[i] = *(const uint4*)(src);
            Bv[i] = *(const uint4*)(src + 64);
        }
    }

    #pragma unroll
    for (int pi = 0; pi < 2; ++pi) {
        const int p = 2 * pblk + pi;
        if (pi) __syncthreads();             // prev iteration's A3 reads done

        // zero K-pad (units 10,11 = kc 80..95; A3 clobbered them last iter)
        #pragma unroll
        for (int i = 0; i < 4; ++i) {
            int idx = tid + i * 256;         // 0..1023
            int row = idx >> 3, d = idx & 7;
            int u = 10 + (d >> 2);
            sm[row * 64 + ((u ^ SIG(row)) << 2) + (d & 3)] = 0;
        }
        // write Ts(p): transpose kc-pairs into swizzled rows
        #pragma unroll
        for (int i = 0; i < 3; ++i) {
            int it = tid + i * 256;
            if (it < 640) {
                int a2 = it >> 4, wq = it & 15;
                const uint32* av = (const uint32*)&Av[i];
                const uint32* bv = (const uint32*)&Bv[i];
                int u = a2 >> 2, lo = a2 & 3;
                #pragma unroll
                for (int j = 0; j < 4; ++j) {
                    int r0 = wq * 8 + 2 * j, r1 = r0 + 1;
                    sm[r0 * 64 + ((u ^ SIG(r0)) << 2) + lo] = (av[j] & 0xffffu) | (bv[j] << 16);
                    sm[r1 * 64 + ((u ^ SIG(r1)) << 2) + lo] = (av[j] >> 16) | (bv[j] & 0xffff0000u);
                }
            }
        }
        __syncthreads();

        // prefetch t1(p1): latency hides under stage2 + A3 + stage3 of p0
        if (pi == 0) {
            #pragma unroll
            for (int i = 0; i < 3; ++i) {
                int it = tid + i * 256;
                if (it < 640) {
                    int a2 = it >> 4, wq = it & 15;
                    const uint32* src = t1base + 5120 + a2 * 128 + wq * 4;
                    Av[i] = *(const uint4*)(src);
                    Bv[i] = *(const uint4*)(src + 64);
                }
            }
        }

        // ---- stage2: rows w = wave*32 + mi*16 + n16
        f32x4 acc[2][5];
        #pragma unroll
        for (int mi = 0; mi < 2; ++mi)
            #pragma unroll
            for (int ni = 0; ni < 5; ++ni) acc[mi][ni] = (f32x4)0.f;

        #pragma unroll
        for (int ks = 0; ks < 3; ++ks) {
            bf16x8 Af[2], Bf[5];
            #pragma unroll
            for (int mi = 0; mi < 2; ++mi) {
                int row = wave * 32 + mi * 16 + n16;
                Af[mi] = frag16(sm + row * 64 + (((ks * 4 + g) ^ SIG(row)) << 2));
            }
            #pragma unroll
            for (int ni = 0; ni < 5; ++ni)
                Bf[ni] = frag16(coefF + ((size_t)(ni * 3 + ks) * 64 + lane) * 8);
            #pragma unroll
            for (int mi = 0; mi < 2; ++mi)
                #pragma unroll
                for (int ni = 0; ni < 5; ++ni)
                    acc[mi][ni] = MFMA(Af[mi], Bf[ni], acc[mi][ni]);
        }
        __syncthreads();   // Ts reads done; A3 may overwrite

        // s -> A3: row u = n16 (16 rows, stride 648 ushort), col l*128+w
        {
            ushort16* A3 = (ushort16*)sm;
            #pragma unroll
            for (int mi = 0; mi < 2; ++mi)
                #pragma unroll
                for (int ni = 0; ni < 5; ++ni) {
                    int wcol = wave * 32 + mi * 16 + g * 4;
                    uint2 d;
                    d.x = pkbf(acc[mi][ni][0], acc[mi][ni][1]);
                    d.y = pkbf(acc[mi][ni][2], acc[mi][ni][3]);
                    *(uint2*)(A3 + n16 * 648 + ni * 128 + wcol) = d;
                }
        }
        __syncthreads();

        // ---- stage3: M=16 (u), wave owns 32 q; B from registers. ks 4..19.
        const ushort16* A3r = (const ushort16*)sm;
        f32x4 c3[2];
        c3[0] = (f32x4)0.f; c3[1] = (f32x4)0.f;
        #pragma unroll
        for (int ks = 4; ks < 20; ++ks) {
            bf16x8 Aa = frag16(A3r + n16 * 648 + ks * 32 + g * 8);
            c3[0] = MFMA(Aa, B3[ks - 4], c3[0]);
            c3[1] = MFMA(Aa, B3[16 + ks - 4], c3[1]);
        }

        #pragma unroll
        for (int nt = 0; nt < 2; ++nt)
            #pragma unroll
            for (int r = 0; r < 4; ++r) {
                int u = g * 4 + r;
                int q = wave * 32 + nt * 16 + n16;
                // l=0 identity contribution: + s[u][w=q] (bf16 in A3 col q)
                uint32 bf = ((uint32)A3r[u * 648 + q]) << 16;
                float l0 = __uint_as_float(bf);
                out[(((size_t)(b * NU + u)) * LEN + p) * LEN + q] = c3[nt][r] + l0;
            }
    }
}

extern "C" void kernel_launch(void* const* d_in, const int* in_sizes, int n_in,
                              void* d_out, int out_size, void* d_ws, size_t ws_size,
                              hipStream_t stream) {
    const float* x     = (const float*)d_in[0];
    const float* coefs = (const float*)d_in[1];
    const float* cheb1 = (const float*)d_in[2];
    const float* cheb2 = (const float*)d_in[3];
    float* out = (float*)d_out;

    const size_t xF_bytes  = (size_t)NB * NC * 16384 * sizeof(ushort16);   // 16.8 MB
    const size_t aux_bytes = 163840 + 163840 + 15360;                      // cheb1F + cheb2F + coefF
    size_t off = (ws_size - aux_bytes - xF_bytes) & ~(size_t)255;
    ushort16* cheb1F = (ushort16*)((char*)d_ws + off);
    ushort16* cheb2F = cheb1F + 81920;
    ushort16* coefF  = cheb2F + 81920;
    ushort16* xF     = coefF + 7680;
    ushort16* t1 = (ushort16*)d_ws;

    const size_t per_b = (size_t)LEN * KC * LEN * sizeof(ushort16);        // 2.62 MB
    int chunk = (int)(off / per_b);
    if (chunk < 1) chunk = 1;
    if (chunk > NB) chunk = NB;

    hipLaunchKernelGGL(kprep, dim3(1182), dim3(256), 0, stream,
                       x, coefs, cheb1, cheb2, xF, cheb1F, cheb2F, coefF);
    for (int b0 = 0; b0 < NB; b0 += chunk) {
        int cb = (NB - b0 < chunk) ? (NB - b0) : chunk;
        hipLaunchKernelGGL(k1_mfma, dim3(NC, cb, 8), dim3(256), 0, stream,
                           xF, cheb1F, x, t1, b0);
        hipLaunchKernelGGL(k2_mfma, dim3(64, cb), dim3(256), 0, stream,
                           t1, coefF, cheb2F, out, b0);
    }
}

// Round 13
// 154.801 us; speedup vs baseline: 2.2951x; 1.0017x over previous
//
#include <hip/hip_runtime.h>
#include <hip/hip_bf16.h>

#define LEN 128
#define NB 32
#define NC 16
#define NU 16
#define NK 5
#define KC 80          // (k,c) pairs
#define KCP 96         // padded K for stage2

typedef unsigned int uint32;
typedef unsigned short ushort16;
typedef __attribute__((ext_vector_type(8))) short bf16x8;
typedef __attribute__((ext_vector_type(4))) float f32x4;

#define MFMA(a, b, c) __builtin_amdgcn_mfma_f32_16x16x32_bf16(a, b, c, 0, 0, 0)

// XOR swizzle of the 16B-unit index within a 64-dword row (16 units).
#define SIG(r) (((r) & 15) ^ (((r) >> 3) & 15))

static __device__ inline ushort16 f2bf(float f) {
    union { float f; uint32 u; } v; v.f = f;
    uint32 u = v.u;
    uint32 r = (u + 0x7fffu + ((u >> 16) & 1u)) >> 16;   // RNE
    return (ushort16)r;
}
static __device__ inline uint32 pkbf(float a, float b) {   // low=a, high=b (verified r0-r12)
    return (uint32)f2bf(a) | ((uint32)f2bf(b) << 16);
}
static __device__ inline bf16x8 frag16(const void* p) {    // 16B-aligned
    return *(const bf16x8*)p;
}

// ---------------- kprep: blocks 0..511 = x->xF transpose; 512..1181 = const operands ----------------
__global__ __launch_bounds__(256) void kprep(const float* __restrict__ x,
                                             const float* __restrict__ coefs,
                                             const float* __restrict__ cheb1,
                                             const float* __restrict__ cheb2,
                                             ushort16* __restrict__ xF,
                                             ushort16* __restrict__ cheb1F,
                                             ushort16* __restrict__ cheb2F,
                                             ushort16* __restrict__ coefF) {
    __shared__ __align__(16) uint32 Xs[128 * 64];   // [w][h-pair units swizzled]
    const int blk = blockIdx.x, tid = threadIdx.x;
    if (blk < 512) {
        const int bc = blk;
        const float* xp = x + (size_t)bc * (LEN * LEN);
        {
            int w = tid & 127, hg = tid >> 7;
            #pragma unroll
            for (int uu = 0; uu < 8; ++uu) {
                int u = hg * 8 + uu;
                uint4 d;
                uint32* dp = (uint32*)&d;
                #pragma unroll
                for (int t = 0; t < 4; ++t) {
                    int h2 = u * 4 + t;
                    dp[t] = pkbf(xp[(2 * h2) * LEN + w], xp[(2 * h2 + 1) * LEN + w]);
                }
                *(uint4*)(Xs + w * 64 + ((u ^ SIG(w)) << 2)) = d;
            }
        }
        __syncthreads();
        ushort16* dst = xF + (size_t)bc * 16384;
        #pragma unroll
        for (int i = 0; i < 8; ++i) {
            int n = tid + i * 256;               // 0..2047 fragment-units of 16B
            int lane = n & 63, fk = n >> 6;      // fk = mt*4+ks
            int wrow = (fk >> 2) * 16 + (lane & 15);
            int u = (fk & 3) * 4 + (lane >> 4);
            uint4 v = *(const uint4*)(Xs + wrow * 64 + ((u ^ SIG(wrow)) << 2));
            *(uint4*)(dst + (size_t)n * 8) = v;
        }
    } else {
        int i = (blk - 512) * 256 + tid;         // 0..171519
        if (i < 81920) {
            int j = i & 7, lane = (i >> 3) & 63, ks = (i >> 9) & 3, nt = i >> 11;
            int kp = nt * 16 + (lane & 15);
            int k = kp >> 7, p = kp & 127;
            int h = ks * 32 + ((lane >> 4) << 3) + j;
            cheb1F[i] = f2bf(cheb1[(k * LEN + h) * LEN + p]);
        } else if (i < 163840) {
            int i2 = i - 81920;
            int j = i2 & 7, lane = (i2 >> 3) & 63, t = i2 >> 9;
            int ks = t % 20, nt = t / 20;
            int q = nt * 16 + (lane & 15);
            int lw = ks * 32 + ((lane >> 4) << 3) + j;
            int l = lw >> 7, w = lw & 127;
            cheb2F[i2] = f2bf(cheb2[(l * LEN + w) * LEN + q]);
        } else {
            int i3 = i - 163840;
            int j = i3 & 7, lane = (i3 >> 3) & 63, t = i3 >> 9;
            int ks = t % 3, nt = t / 3;
            int lu = nt * 16 + (lane & 15);
            int l = lu >> 4, u = lu & 15;
            int kc = ks * 32 + ((lane >> 4) << 3) + j;
            int k = kc >> 4, c = kc & 15;
            coefF[i3] = (kc < KC) ? f2bf(coefs[((k * NK + l) * NC + c) * NU + u]) : (ushort16)0;
        }
    }
}

// ---------------- k1: t1[bl][p][kc][w] = sum_h cheb1[k][h][p]*x[b][c][h][w]
// T_0 = I  =>  t1[p][k=0][c][w] = bf16(x[b][c][p][w]) is a direct copy (done by
// z==0 blocks). GEMM covers kp in [128,640): grid (c, bl, z 0..7), 64 kp/seg.
// cheb1F segment (16KB) staged once in LDS (SIG-swizzled); waves 2x2 over
// (w-half, kp-half). Epilogue bounces through 16KB LDS for coalesced stores.
__global__ __launch_bounds__(256, 4) void k1_mfma(const ushort16* __restrict__ xF,
                                                  const ushort16* __restrict__ cheb1F,
                                                  const float* __restrict__ x,
                                                  ushort16* __restrict__ t1, int b0) {
    __shared__ __align__(16) uint32 Ls[64 * 64];   // cheb1F seg [kp_local][h-units swz]
    __shared__ __align__(16) uint32 Bs[64 * 64];   // bounce: 64 kp-rows x 128 w bf16, swz
    const int c = blockIdx.x, bl = blockIdx.y, z = blockIdx.z;
    const int b = b0 + bl;
    const int tid = threadIdx.x;
    const int lane = tid & 63, wave = tid >> 6;
    const int m16 = lane & 15, g = lane >> 4;
    const int wm = wave >> 1, wn = wave & 1;       // 2x2 wave grid

    // stage cheb1F segment -> Ls (swizzled); unit u=(nt,ks,lane)
    #pragma unroll
    for (int i = 0; i < 4; ++i) {
        int u = tid + i * 256;            // 0..1023
        int ln = u & 63, ks = (u >> 6) & 3, nt = u >> 8;
        uint4 v = *(const uint4*)(cheb1F + ((size_t)(((8 + z * 4 + nt) * 4 + ks) * 64 + ln)) * 8);
        int row = nt * 16 + (ln & 15), hu = ks * 4 + (ln >> 4);
        *(uint4*)(Ls + row * 64 + ((hu ^ SIG(row)) << 2)) = v;
    }

    // z==0: k=0 identity copy t1[p][kc=c][w] = bf16(x[b][c][p][w])
    if (z == 0) {
        const float* xp = x + (size_t)(b * NC + c) * (LEN * LEN);
        int p = tid >> 1, half = tid & 1;
        const float4* src = (const float4*)(xp + p * LEN + half * 64);
        ushort16* dst = t1 + ((size_t)(bl * LEN + p) * KC + c) * LEN + half * 64;
        #pragma unroll
        for (int i = 0; i < 16; ++i) {
            float4 v = src[i];
            uint2 d;
            d.x = pkbf(v.x, v.y);
            d.y = pkbf(v.z, v.w);
            *(uint2*)(dst + i * 4) = d;
        }
    }
    __syncthreads();

    const ushort16* xFb = xF + ((size_t)(b * NC + c)) * 16384;

    f32x4 acc[4][2];
    #pragma unroll
    for (int mi = 0; mi < 4; ++mi)
        #pragma unroll
        for (int ni = 0; ni < 2; ++ni) acc[mi][ni] = (f32x4)0.f;

    #pragma unroll
    for (int ks = 0; ks < 4; ++ks) {
        bf16x8 Af[4], Bf[2];
        #pragma unroll
        for (int mi = 0; mi < 4; ++mi) {
            int mt = wm * 4 + mi;
            Af[mi] = frag16(xFb + ((size_t)(mt * 4 + ks) * 64 + lane) * 8);
        }
        #pragma unroll
        for (int ni = 0; ni < 2; ++ni) {
            int row = (wn * 2 + ni) * 16 + m16;
            int hu = ks * 4 + g;
            Bf[ni] = frag16(Ls + row * 64 + ((hu ^ SIG(row)) << 2));
        }
        #pragma unroll
        for (int mi = 0; mi < 4; ++mi)
            #pragma unroll
            for (int ni = 0; ni < 2; ++ni)
                acc[mi][ni] = MFMA(Af[mi], Bf[ni], acc[mi][ni]);
    }

    // bounce: D element (m = w = (wm*4+mi)*16+g*4+r, n = kp_local = (wn*2+ni)*16+m16)
    #pragma unroll
    for (int ni = 0; ni < 2; ++ni)
        #pragma unroll
        for (int mi = 0; mi < 4; ++mi) {
            int rr = (wn * 2 + ni) * 16 + m16;
            int wu = (wm * 4 + mi) * 16 + g * 4;      // ushort col (w)
            uint2 d;
            d.x = pkbf(acc[mi][ni][0], acc[mi][ni][1]);
            d.y = pkbf(acc[mi][ni][2], acc[mi][ni][3]);
            int u = wu >> 3;
            *(uint2*)(Bs + rr * 64 + ((u ^ SIG(rr)) << 2) + ((wu >> 1) & 3)) = d;
        }
    __syncthreads();

    // read-out + coalesced store (256B runs); kp = 128 + z*64 + rr
    #pragma unroll
    for (int i = 0; i < 4; ++i) {
        int n = tid + i * 256;                 // 0..1023
        int rr = n >> 4, wsg = n & 15;
        uint4 v = *(const uint4*)(Bs + rr * 64 + ((wsg ^ SIG(rr)) << 2));
        int kp = 128 + z * 64 + rr;
        int k = kp >> 7, p = kp & 127;
        *(uint4*)(t1 + ((size_t)((bl * LEN + p) * KC + k * NC + c)) * LEN + wsg * 8) = v;
    }
}

// ---------------- k2: per (p, bl) block, 512 threads = 8 waves on ONE p.
// Same 32KB LDS and phase math as the verified r7 kernel, but per-wave phases
// are half as long and a filled CU holds 3 blocks x 8 = 24 waves (vs ~11) ->
// wave-level latency hiding without any extra register state.
// stage2: s[w(128)][lu(80)] = Ts[w][kc] x coefF (K=96, zero-padded); wave owns
// 16 w-rows. stage3: out[u(16)][q(128)] = A3[u][lw] x cheb2F, ks 4..19 (l=0
// identity added in epilogue); wave owns 16 q.
__global__ __launch_bounds__(512, 6) void k2_mfma(const ushort16* __restrict__ t1,
                                                  const ushort16* __restrict__ coefF,
                                                  const ushort16* __restrict__ cheb2F,
                                                  float* __restrict__ out, int b0) {
    __shared__ __align__(16) uint32 sm[128 * 64];   // 32KB: Ts [w][kc units swz]; A3 (16x648 ush) aliases
    const int p = blockIdx.x, bl = blockIdx.y, b = b0 + bl;
    const int tid = threadIdx.x;                    // 0..511
    const int lane = tid & 63, wave = tid >> 6;     // wave 0..7
    const int n16 = lane & 15, g = lane >> 4;

    // issue t1 global loads FIRST (longest latency in the chain)
    const uint32* t1u = (const uint32*)(t1 + (size_t)(bl * LEN + p) * (KC * LEN));
    uint4 Av[2], Bv[2];
    #pragma unroll
    for (int i = 0; i < 2; ++i) {
        int it = tid + i * 512;              // 0..1023; active < 640
        if (it < 640) {
            int a2 = it >> 4, wq = it & 15;  // a2 = kc-pair 0..39
            const uint32* src = t1u + a2 * 128 + wq * 4;
            Av[i] = *(const uint4*)(src);
            Bv[i] = *(const uint4*)(src + 64);
        }
    }
    // zero K-pad (dw 40..47 = units 10,11) while loads are in flight
    #pragma unroll
    for (int i = 0; i < 2; ++i) {
        int idx = tid + i * 512;             // 0..1023
        int row = idx >> 3, d = idx & 7;
        int u = 10 + (d >> 2);
        sm[row * 64 + ((u ^ SIG(row)) << 2) + (d & 3)] = 0;
    }
    // transpose kc-pairs into swizzled rows (verified shift/mask merges)
    #pragma unroll
    for (int i = 0; i < 2; ++i) {
        int it = tid + i * 512;
        if (it < 640) {
            int a2 = it >> 4, wq = it & 15;
            const uint32* av = (const uint32*)&Av[i];
            const uint32* bv = (const uint32*)&Bv[i];
            int u = a2 >> 2, lo = a2 & 3;
            #pragma unroll
            for (int j = 0; j < 4; ++j) {
                int r0 = wq * 8 + 2 * j, r1 = r0 + 1;
                sm[r0 * 64 + ((u ^ SIG(r0)) << 2) + lo] = (av[j] & 0xffffu) | (bv[j] << 16);
                sm[r1 * 64 + ((u ^ SIG(r1)) << 2) + lo] = (av[j] >> 16) | (bv[j] & 0xffff0000u);
            }
        }
    }
    __syncthreads();

    // ---- stage2: wave owns rows w = wave*16 + n16 (one 16-row m-tile)
    f32x4 acc[5];
    #pragma unroll
    for (int ni = 0; ni < 5; ++ni) acc[ni] = (f32x4)0.f;

    const int row2 = wave * 16 + n16;
    #pragma unroll
    for (int ks = 0; ks < 3; ++ks) {
        bf16x8 Af = frag16(sm + row2 * 64 + (((ks * 4 + g) ^ SIG(row2)) << 2));
        bf16x8 Bf[5];
        #pragma unroll
        for (int ni = 0; ni < 5; ++ni)
            Bf[ni] = frag16(coefF + ((size_t)(ni * 3 + ks) * 64 + lane) * 8);
        #pragma unroll
        for (int ni = 0; ni < 5; ++ni)
            acc[ni] = MFMA(Af, Bf[ni], acc[ni]);
    }
    __syncthreads();   // Ts reads done; A3 may overwrite

    // s -> A3: row u = n16 (16 rows, stride 648 ushort), col l*128+w
    // D element mapping: acc[ni][r] = s[w = wave*16 + g*4 + r][lu = ni*16 + n16]
    {
        ushort16* A3 = (ushort16*)sm;
        int wcol = wave * 16 + g * 4;
        #pragma unroll
        for (int ni = 0; ni < 5; ++ni) {
            uint2 d;
            d.x = pkbf(acc[ni][0], acc[ni][1]);
            d.y = pkbf(acc[ni][2], acc[ni][3]);
            *(uint2*)(A3 + n16 * 648 + ni * 128 + wcol) = d;
        }
    }
    __syncthreads();

    // ---- stage3: M=16 (u), wave owns 16 q (q-tile = wave). ks 4..19 only.
    const ushort16* A3r = (const ushort16*)sm;
    f32x4 c3 = (f32x4)0.f;
    #pragma unroll
    for (int ks = 4; ks < 20; ++ks) {
        bf16x8 Aa = frag16(A3r + n16 * 648 + ks * 32 + g * 8);
        bf16x8 Bb = frag16(cheb2F + ((size_t)(wave * 20 + ks) * 64 + lane) * 8);
        c3 = MFMA(Aa, Bb, c3);
    }

    #pragma unroll
    for (int r = 0; r < 4; ++r) {
        int u = g * 4 + r;
        int q = wave * 16 + n16;
        // l=0 identity contribution: + s[u][w=q] (bf16 in A3 col q)
        uint32 bf = ((uint32)A3r[u * 648 + q]) << 16;
        float l0 = __uint_as_float(bf);
        out[(((size_t)(b * NU + u)) * LEN + p) * LEN + q] = c3[r] + l0;
    }
}

extern "C" void kernel_launch(void* const* d_in, const int* in_sizes, int n_in,
                              void* d_out, int out_size, void* d_ws, size_t ws_size,
                              hipStream_t stream) {
    const float* x     = (const float*)d_in[0];
    const float* coefs = (const float*)d_in[1];
    const float* cheb1 = (const float*)d_in[2];
    const float* cheb2 = (const float*)d_in[3];
    float* out = (float*)d_out;

    const size_t xF_bytes  = (size_t)NB * NC * 16384 * sizeof(ushort16);   // 16.8 MB
    const size_t aux_bytes = 163840 + 163840 + 15360;                      // cheb1F + cheb2F + coefF
    size_t off = (ws_size - aux_bytes - xF_bytes) & ~(size_t)255;
    ushort16* cheb1F = (ushort16*)((char*)d_ws + off);
    ushort16* cheb2F = cheb1F + 81920;
    ushort16* coefF  = cheb2F + 81920;
    ushort16* xF     = coefF + 7680;
    ushort16* t1 = (ushort16*)d_ws;

    const size_t per_b = (size_t)LEN * KC * LEN * sizeof(ushort16);        // 2.62 MB
    int chunk = (int)(off / per_b);
    if (chunk < 1) chunk = 1;
    if (chunk > NB) chunk = NB;

    hipLaunchKernelGGL(kprep, dim3(1182), dim3(256), 0, stream,
                       x, coefs, cheb1, cheb2, xF, cheb1F, cheb2F, coefF);
    for (int b0 = 0; b0 < NB; b0 += chunk) {
        int cb = (NB - b0 < chunk) ? (NB - b0) : chunk;
        hipLaunchKernelGGL(k1_mfma, dim3(NC, cb, 8), dim3(256), 0, stream,
                           xF, cheb1F, x, t1, b0);
        hipLaunchKernelGGL(k2_mfma, dim3(LEN, cb), dim3(512), 0, stream,
                           t1, coefF, cheb2F, out, b0);
    }
}

// Round 14
// 149.496 us; speedup vs baseline: 2.3766x; 1.0355x over previous
//
#include <hip/hip_runtime.h>
#include <hip/hip_bf16.h>

#define LEN 128
#define NB 32
#define NC 16
#define NU 16
#define NK 5
#define KC 80          // (k,c) pairs
#define KCP 96         // padded K for stage2

typedef unsigned int uint32;
typedef unsigned short ushort16;
typedef __attribute__((ext_vector_type(8))) short bf16x8;
typedef __attribute__((ext_vector_type(4))) float f32x4;

#define MFMA(a, b, c) __builtin_amdgcn_mfma_f32_16x16x32_bf16(a, b, c, 0, 0, 0)

// XOR swizzle of the 16B-unit index within a 64-dword row (16 units).
#define SIG(r) (((r) & 15) ^ (((r) >> 3) & 15))

static __device__ inline ushort16 f2bf(float f) {
    union { float f; uint32 u; } v; v.f = f;
    uint32 u = v.u;
    uint32 r = (u + 0x7fffu + ((u >> 16) & 1u)) >> 16;   // RNE
    return (ushort16)r;
}
static __device__ inline uint32 pkbf(float a, float b) {   // low=a, high=b (verified r0-r13)
    return (uint32)f2bf(a) | ((uint32)f2bf(b) << 16);
}
static __device__ inline bf16x8 frag16(const void* p) {    // 16B-aligned
    return *(const bf16x8*)p;
}

// ---------------- kprep: blocks 0..511 = x->xF transpose; 512..1181 = const operands ----------------
__global__ __launch_bounds__(256) void kprep(const float* __restrict__ x,
                                             const float* __restrict__ coefs,
                                             const float* __restrict__ cheb1,
                                             const float* __restrict__ cheb2,
                                             ushort16* __restrict__ xF,
                                             ushort16* __restrict__ cheb1F,
                                             ushort16* __restrict__ cheb2F,
                                             ushort16* __restrict__ coefF) {
    __shared__ __align__(16) uint32 Xs[128 * 64];   // [w][h-pair units swizzled]
    const int blk = blockIdx.x, tid = threadIdx.x;
    if (blk < 512) {
        const int bc = blk;
        const float* xp = x + (size_t)bc * (LEN * LEN);
        {
            int w = tid & 127, hg = tid >> 7;
            #pragma unroll
            for (int uu = 0; uu < 8; ++uu) {
                int u = hg * 8 + uu;
                uint4 d;
                uint32* dp = (uint32*)&d;
                #pragma unroll
                for (int t = 0; t < 4; ++t) {
                    int h2 = u * 4 + t;
                    dp[t] = pkbf(xp[(2 * h2) * LEN + w], xp[(2 * h2 + 1) * LEN + w]);
                }
                *(uint4*)(Xs + w * 64 + ((u ^ SIG(w)) << 2)) = d;
            }
        }
        __syncthreads();
        ushort16* dst = xF + (size_t)bc * 16384;
        #pragma unroll
        for (int i = 0; i < 8; ++i) {
            int n = tid + i * 256;               // 0..2047 fragment-units of 16B
            int lane = n & 63, fk = n >> 6;      // fk = mt*4+ks
            int wrow = (fk >> 2) * 16 + (lane & 15);
            int u = (fk & 3) * 4 + (lane >> 4);
            uint4 v = *(const uint4*)(Xs + wrow * 64 + ((u ^ SIG(wrow)) << 2));
            *(uint4*)(dst + (size_t)n * 8) = v;
        }
    } else {
        int i = (blk - 512) * 256 + tid;         // 0..171519
        if (i < 81920) {
            int j = i & 7, lane = (i >> 3) & 63, ks = (i >> 9) & 3, nt = i >> 11;
            int kp = nt * 16 + (lane & 15);
            int k = kp >> 7, p = kp & 127;
            int h = ks * 32 + ((lane >> 4) << 3) + j;
            cheb1F[i] = f2bf(cheb1[(k * LEN + h) * LEN + p]);
        } else if (i < 163840) {
            int i2 = i - 81920;
            int j = i2 & 7, lane = (i2 >> 3) & 63, t = i2 >> 9;
            int ks = t % 20, nt = t / 20;
            int q = nt * 16 + (lane & 15);
            int lw = ks * 32 + ((lane >> 4) << 3) + j;
            int l = lw >> 7, w = lw & 127;
            cheb2F[i2] = f2bf(cheb2[(l * LEN + w) * LEN + q]);
        } else {
            int i3 = i - 163840;
            int j = i3 & 7, lane = (i3 >> 3) & 63, t = i3 >> 9;
            int ks = t % 3, nt = t / 3;
            int lu = nt * 16 + (lane & 15);
            int l = lu >> 4, u = lu & 15;
            int kc = ks * 32 + ((lane >> 4) << 3) + j;
            int k = kc >> 4, c = kc & 15;
            coefF[i3] = (kc < KC) ? f2bf(coefs[((k * NK + l) * NC + c) * NU + u]) : (ushort16)0;
        }
    }
}

// ---------------- k1: t1[bl][p][kc][w] = sum_h cheb1[k][h][p]*x[b][c][h][w]
// k=0 plane NEVER materialized (T_0 = I; k2 reads x directly). GEMM covers
// kp in [128,640): grid (c, bl, z 0..7), 64 kp/seg. LDS-free GEMM with
// wave-contiguous 1KB fragment reads; 16KB LDS bounce for coalesced stores.
__global__ __launch_bounds__(256, 5) void k1_mfma(const ushort16* __restrict__ xF,
                                                  const ushort16* __restrict__ cheb1F,
                                                  ushort16* __restrict__ t1, int b0) {
    __shared__ __align__(16) uint32 Bs[64 * 64];   // bounce: 64 kp-rows x 128 w bf16, swizzled
    const int c = blockIdx.x, bl = blockIdx.y, z = blockIdx.z;
    const int b = b0 + bl;
    const int tid = threadIdx.x;
    const int lane = tid & 63, wm = tid >> 6;      // wave = m-quarter
    const int m16 = lane & 15, g = lane >> 4;

    const ushort16* xFb = xF + ((size_t)(b * NC + c)) * 16384;

    f32x4 acc[2][4];
    #pragma unroll
    for (int mi = 0; mi < 2; ++mi)
        #pragma unroll
        for (int ni = 0; ni < 4; ++ni) acc[mi][ni] = (f32x4)0.f;

    #pragma unroll
    for (int ks = 0; ks < 4; ++ks) {
        bf16x8 Af[2], Bf[4];
        #pragma unroll
        for (int mi = 0; mi < 2; ++mi) {
            int mt = wm * 2 + mi;
            Af[mi] = frag16(xFb + ((size_t)(mt * 4 + ks) * 64 + lane) * 8);
        }
        #pragma unroll
        for (int ni = 0; ni < 4; ++ni) {
            int nt = 8 + z * 4 + ni;
            Bf[ni] = frag16(cheb1F + ((size_t)(nt * 4 + ks) * 64 + lane) * 8);
        }
        #pragma unroll
        for (int mi = 0; mi < 2; ++mi)
            #pragma unroll
            for (int ni = 0; ni < 4; ++ni)
                acc[mi][ni] = MFMA(Af[mi], Bf[ni], acc[mi][ni]);
    }

    // bounce: D element (m = w = wm*32+mi*16+g*4+r, n = rr = ni*16+m16)
    #pragma unroll
    for (int ni = 0; ni < 4; ++ni)
        #pragma unroll
        for (int mi = 0; mi < 2; ++mi) {
            int rr = ni * 16 + m16;
            int wu = wm * 32 + mi * 16 + g * 4;       // ushort col (w)
            uint2 d;
            d.x = pkbf(acc[mi][ni][0], acc[mi][ni][1]);
            d.y = pkbf(acc[mi][ni][2], acc[mi][ni][3]);
            int u = wu >> 3;
            *(uint2*)(Bs + rr * 64 + ((u ^ SIG(rr)) << 2) + ((wu >> 1) & 3)) = d;
        }
    __syncthreads();

    // read-out + coalesced store (256B runs); kp = 128 + z*64 + rr
    #pragma unroll
    for (int i = 0; i < 4; ++i) {
        int n = tid + i * 256;                 // 0..1023
        int rr = n >> 4, wsg = n & 15;
        uint4 v = *(const uint4*)(Bs + rr * 64 + ((wsg ^ SIG(rr)) << 2));
        int kp = 128 + z * 64 + rr;
        int k = kp >> 7, p = kp & 127;
        *(uint4*)(t1 + ((size_t)((bl * LEN + p) * KC + k * NC + c)) * LEN + wsg * 8) = v;
    }
}

// ---------------- k2: per (p, bl) block (1 p-slice, 32KB LDS, 5 blocks/CU)
// Ts rows kc 0..15 (k=0, T_0=I) staged DIRECTLY from x (f32, L3-resident);
// rows 16..79 from t1. stage2: s[w][lu] = Ts[w][kc] x coefF (K=96, padded);
// stage3: out[u][q] = A3[u][lw] x cheb2F, ks 4..19 (l=0 identity in epilogue).
__global__ __launch_bounds__(256, 5) void k2_mfma(const ushort16* __restrict__ t1,
                                                  const float* __restrict__ x,
                                                  const ushort16* __restrict__ coefF,
                                                  const ushort16* __restrict__ cheb2F,
                                                  float* __restrict__ out, int b0) {
    __shared__ __align__(16) uint32 sm[128 * 64];   // 32KB: Ts [w][kc units swz]; A3 (16x648 ush) aliases
    const int p = blockIdx.x, bl = blockIdx.y, b = b0 + bl;
    const int tid = threadIdx.x;
    const int lane = tid & 63, wave = tid >> 6;
    const int n16 = lane & 15, g = lane >> 4;

    // issue t1 global loads FIRST (kc rows 16..79 -> pair cols a2 = 8..39)
    const uint32* t1u = (const uint32*)(t1 + (size_t)(bl * LEN + p) * (KC * LEN));
    uint4 Av[2], Bv[2];
    #pragma unroll
    for (int i = 0; i < 2; ++i) {
        int it = tid + i * 256;              // 0..511, all active
        int a2 = 8 + (it >> 4), wq = it & 15;
        const uint32* src = t1u + a2 * 128 + wq * 4;
        Av[i] = *(const uint4*)(src);
        Bv[i] = *(const uint4*)(src + 64);
    }
    // k=0 rows from x: pair j = tid>>5 (c = 2j, 2j+1), w0 = (tid&31)*4
    float4 X0, X1;
    {
        int j = tid >> 5, w0 = (tid & 31) << 2;
        const float* xb = x + ((size_t)(b * NC) * LEN + p) * LEN;
        const float* xa = xb + (size_t)(2 * j) * (LEN * LEN);
        X0 = *(const float4*)(xa + w0);
        X1 = *(const float4*)(xa + LEN * LEN + w0);
    }
    // zero K-pad (dw 40..47 = units 10,11) while loads are in flight
    #pragma unroll
    for (int i = 0; i < 4; ++i) {
        int idx = tid + i * 256;             // 0..1023
        int row = idx >> 3, d = idx & 7;
        int u = 10 + (d >> 2);
        sm[row * 64 + ((u ^ SIG(row)) << 2) + (d & 3)] = 0;
    }
    // write k=0 dword-cols (a2 = j = 0..7): sm[w][col j] = pk(x[2j][p][w], x[2j+1][p][w])
    {
        int j = tid >> 5, w0 = (tid & 31) << 2;
        const float* f0 = (const float*)&X0;
        const float* f1 = (const float*)&X1;
        int u0 = j >> 2, lo = j & 3;
        #pragma unroll
        for (int r = 0; r < 4; ++r) {
            int row = w0 + r;
            sm[row * 64 + ((u0 ^ SIG(row)) << 2) + lo] = pkbf(f0[r], f1[r]);
        }
    }
    // transpose t1 kc-pairs into swizzled rows (verified shift/mask merges)
    #pragma unroll
    for (int i = 0; i < 2; ++i) {
        int it = tid + i * 256;
        int a2 = 8 + (it >> 4), wq = it & 15;
        const uint32* av = (const uint32*)&Av[i];
        const uint32* bv = (const uint32*)&Bv[i];
        int u = a2 >> 2, lo = a2 & 3;
        #pragma unroll
        for (int j = 0; j < 4; ++j) {
            int r0 = wq * 8 + 2 * j, r1 = r0 + 1;
            sm[r0 * 64 + ((u ^ SIG(r0)) << 2) + lo] = (av[j] & 0xffffu) | (bv[j] << 16);
            sm[r1 * 64 + ((u ^ SIG(r1)) << 2) + lo] = (av[j] >> 16) | (bv[j] & 0xffff0000u);
        }
    }
    __syncthreads();

    // ---- stage2: rows w = wave*32 + mi*16 + n16
    f32x4 acc[2][5];
    #pragma unroll
    for (int mi = 0; mi < 2; ++mi)
        #pragma unroll
        for (int ni = 0; ni < 5; ++ni) acc[mi][ni] = (f32x4)0.f;

    #pragma unroll
    for (int ks = 0; ks < 3; ++ks) {
        bf16x8 Af[2], Bf[5];
        #pragma unroll
        for (int mi = 0; mi < 2; ++mi) {
            int row = wave * 32 + mi * 16 + n16;
            Af[mi] = frag16(sm + row * 64 + (((ks * 4 + g) ^ SIG(row)) << 2));
        }
        #pragma unroll
        for (int ni = 0; ni < 5; ++ni)
            Bf[ni] = frag16(coefF + ((size_t)(ni * 3 + ks) * 64 + lane) * 8);
        #pragma unroll
        for (int mi = 0; mi < 2; ++mi)
            #pragma unroll
            for (int ni = 0; ni < 5; ++ni)
                acc[mi][ni] = MFMA(Af[mi], Bf[ni], acc[mi][ni]);
    }
    __syncthreads();   // Ts reads done; A3 may overwrite

    // s -> A3: row u = n16 (16 rows, stride 648 ushort), col l*128+w
    {
        ushort16* A3 = (ushort16*)sm;
        #pragma unroll
        for (int mi = 0; mi < 2; ++mi)
            #pragma unroll
            for (int ni = 0; ni < 5; ++ni) {
                int wcol = wave * 32 + mi * 16 + g * 4;
                uint2 d;
                d.x = pkbf(acc[mi][ni][0], acc[mi][ni][1]);
                d.y = pkbf(acc[mi][ni][2], acc[mi][ni][3]);
                *(uint2*)(A3 + n16 * 648 + ni * 128 + wcol) = d;
            }
    }
    __syncthreads();

    // ---- stage3: M=16 (u), wave owns 32 q. Skip l=0 (identity): ks 4..19 only.
    const ushort16* A3r = (const ushort16*)sm;
    f32x4 c3[2];
    c3[0] = (f32x4)0.f; c3[1] = (f32x4)0.f;
    #pragma unroll 4
    for (int ks = 4; ks < 20; ++ks) {
        bf16x8 Aa = frag16(A3r + n16 * 648 + ks * 32 + g * 8);
        #pragma unroll
        for (int nt = 0; nt < 2; ++nt) {
            bf16x8 Bb = frag16(cheb2F + ((size_t)((wave * 2 + nt) * 20 + ks) * 64 + lane) * 8);
            c3[nt] = MFMA(Aa, Bb, c3[nt]);
        }
    }

    #pragma unroll
    for (int nt = 0; nt < 2; ++nt)
        #pragma unroll
        for (int r = 0; r < 4; ++r) {
            int u = g * 4 + r;
            int q = wave * 32 + nt * 16 + n16;
            // l=0 identity contribution: + s[u][w=q] (bf16 in A3 col q)
            uint32 bf = ((uint32)A3r[u * 648 + q]) << 16;
            float l0 = __uint_as_float(bf);
            out[(((size_t)(b * NU + u)) * LEN + p) * LEN + q] = c3[nt][r] + l0;
        }
}

extern "C" void kernel_launch(void* const* d_in, const int* in_sizes, int n_in,
                              void* d_out, int out_size, void* d_ws, size_t ws_size,
                              hipStream_t stream) {
    const float* x     = (const float*)d_in[0];
    const float* coefs = (const float*)d_in[1];
    const float* cheb1 = (const float*)d_in[2];
    const float* cheb2 = (const float*)d_in[3];
    float* out = (float*)d_out;

    const size_t xF_bytes  = (size_t)NB * NC * 16384 * sizeof(ushort16);   // 16.8 MB
    const size_t aux_bytes = 163840 + 163840 + 15360;                      // cheb1F + cheb2F + coefF
    size_t off = (ws_size - aux_bytes - xF_bytes) & ~(size_t)255;
    ushort16* cheb1F = (ushort16*)((char*)d_ws + off);
    ushort16* cheb2F = cheb1F + 81920;
    ushort16* coefF  = cheb2F + 81920;
    ushort16* xF     = coefF + 7680;
    ushort16* t1 = (ushort16*)d_ws;

    const size_t per_b = (size_t)LEN * KC * LEN * sizeof(ushort16);        // 2.62 MB
    int chunk = (int)(off / per_b);
    if (chunk < 1) chunk = 1;
    if (chunk > NB) chunk = NB;

    hipLaunchKernelGGL(kprep, dim3(1182), dim3(256), 0, stream,
                       x, coefs, cheb1, cheb2, xF, cheb1F, cheb2F, coefF);
    for (int b0 = 0; b0 < NB; b0 += chunk) {
        int cb = (NB - b0 < chunk) ? (NB - b0) : chunk;
        hipLaunchKernelGGL(k1_mfma, dim3(NC, cb, 8), dim3(256), 0, stream,
                           xF, cheb1F, t1, b0);
        hipLaunchKernelGGL(k2_mfma, dim3(LEN, cb), dim3(256), 0, stream,
                           t1, x, coefF, cheb2F, out, b0);
    }
}

// Round 15
// 148.710 us; speedup vs baseline: 2.3891x; 1.0053x over previous
//
#include <hip/hip_runtime.h>
#include <hip/hip_bf16.h>

#define LEN 128
#define NB 32
#define NC 16
#define NU 16
#define NK 5
#define KC 80          // (k,c) pairs
#define KCP 96         // padded K for stage2

typedef unsigned int uint32;
typedef unsigned short ushort16;
typedef __attribute__((ext_vector_type(8))) short bf16x8;
typedef __attribute__((ext_vector_type(4))) float f32x4;

#define MFMA(a, b, c) __builtin_amdgcn_mfma_f32_16x16x32_bf16(a, b, c, 0, 0, 0)

// XOR swizzle of the 16B-unit index within a 64-dword row (16 units).
#define SIG(r) (((r) & 15) ^ (((r) >> 3) & 15))

static __device__ inline ushort16 f2bf(float f) {
    union { float f; uint32 u; } v; v.f = f;
    uint32 u = v.u;
    uint32 r = (u + 0x7fffu + ((u >> 16) & 1u)) >> 16;   // RNE
    return (ushort16)r;
}
static __device__ inline uint32 pkbf(float a, float b) {   // low=a, high=b (verified r0-r14)
    return (uint32)f2bf(a) | ((uint32)f2bf(b) << 16);
}
static __device__ inline bf16x8 frag16(const void* p) {    // 16B-aligned
    return *(const bf16x8*)p;
}

// ---------------- kconst: constant operands -> MFMA fragment layout (670 blocks) ----------------
__global__ __launch_bounds__(256) void kconst(const float* __restrict__ coefs,
                                              const float* __restrict__ cheb1,
                                              const float* __restrict__ cheb2,
                                              ushort16* __restrict__ cheb1F,
                                              ushort16* __restrict__ cheb2F,
                                              ushort16* __restrict__ coefF) {
    int i = blockIdx.x * 256 + threadIdx.x;      // 0..171519
    if (i < 81920) {
        int j = i & 7, lane = (i >> 3) & 63, ks = (i >> 9) & 3, nt = i >> 11;
        int kp = nt * 16 + (lane & 15);
        int k = kp >> 7, p = kp & 127;
        int h = ks * 32 + ((lane >> 4) << 3) + j;
        cheb1F[i] = f2bf(cheb1[(k * LEN + h) * LEN + p]);
    } else if (i < 163840) {
        int i2 = i - 81920;
        int j = i2 & 7, lane = (i2 >> 3) & 63, t = i2 >> 9;
        int ks = t % 20, nt = t / 20;
        int q = nt * 16 + (lane & 15);
        int lw = ks * 32 + ((lane >> 4) << 3) + j;
        int l = lw >> 7, w = lw & 127;
        cheb2F[i2] = f2bf(cheb2[(l * LEN + w) * LEN + q]);
    } else {
        int i3 = i - 163840;
        int j = i3 & 7, lane = (i3 >> 3) & 63, t = i3 >> 9;
        int ks = t % 3, nt = t / 3;
        int lu = nt * 16 + (lane & 15);
        int l = lu >> 4, u = lu & 15;
        int kc = ks * 32 + ((lane >> 4) << 3) + j;
        int k = kc >> 4, c = kc & 15;
        coefF[i3] = (kc < KC) ? f2bf(coefs[((k * NK + l) * NC + c) * NU + u]) : (ushort16)0;
    }
}

// ---------------- kfuse: per (c, bl) block — x transpose + full k1 GEMM, fused.
// Phase 1 (verbatim kprep): x[b][c] -> Xs [w][h-pair units, SIG-swizzled] (32KB).
// Phase 2 (8 passes, verbatim k1 math with z->ns): t1[bl][p][kc][w] for
// kp in [128,640), A-fragments read DIRECTLY from Xs (same layout xF had),
// B from cheb1F (L2-hot), 16KB Bs bounce for coalesced t1 stores.
// xF never exists; k=0 plane never materialized (k2 reads x directly; T_0=I).
__global__ __launch_bounds__(256, 3) void kfuse(const float* __restrict__ x,
                                                const ushort16* __restrict__ cheb1F,
                                                ushort16* __restrict__ t1, int b0) {
    __shared__ __align__(16) uint32 Xs[128 * 64];  // 32KB
    __shared__ __align__(16) uint32 Bs[64 * 64];   // 16KB bounce
    const int c = blockIdx.x, bl = blockIdx.y, b = b0 + bl;
    const int tid = threadIdx.x;
    const int lane = tid & 63, wm = tid >> 6;      // wave = m-quarter
    const int m16 = lane & 15, g = lane >> 4;

    // phase 1: transpose + cvt x -> Xs
    {
        const float* xp = x + (size_t)(b * NC + c) * (LEN * LEN);
        int w = tid & 127, hg = tid >> 7;
        #pragma unroll
        for (int uu = 0; uu < 8; ++uu) {
            int u = hg * 8 + uu;
            uint4 d;
            uint32* dp = (uint32*)&d;
            #pragma unroll
            for (int t = 0; t < 4; ++t) {
                int h2 = u * 4 + t;
                dp[t] = pkbf(xp[(2 * h2) * LEN + w], xp[(2 * h2 + 1) * LEN + w]);
            }
            *(uint4*)(Xs + w * 64 + ((u ^ SIG(w)) << 2)) = d;
        }
    }
    __syncthreads();

    // phase 2: 8 segments of 64 kp
    for (int ns = 0; ns < 8; ++ns) {
        f32x4 acc[2][4];
        #pragma unroll
        for (int mi = 0; mi < 2; ++mi)
            #pragma unroll
            for (int ni = 0; ni < 4; ++ni) acc[mi][ni] = (f32x4)0.f;

        #pragma unroll
        for (int ks = 0; ks < 4; ++ks) {
            bf16x8 Af[2], Bf[4];
            #pragma unroll
            for (int mi = 0; mi < 2; ++mi) {
                int wrow = (wm * 2 + mi) * 16 + m16;
                Af[mi] = frag16(Xs + wrow * 64 + (((ks * 4 + g) ^ SIG(wrow)) << 2));
            }
            #pragma unroll
            for (int ni = 0; ni < 4; ++ni) {
                int nt = 8 + ns * 4 + ni;
                Bf[ni] = frag16(cheb1F + ((size_t)(nt * 4 + ks) * 64 + lane) * 8);
            }
            #pragma unroll
            for (int mi = 0; mi < 2; ++mi)
                #pragma unroll
                for (int ni = 0; ni < 4; ++ni)
                    acc[mi][ni] = MFMA(Af[mi], Bf[ni], acc[mi][ni]);
        }

        if (ns) __syncthreads();   // prev pass's readout done before overwriting Bs

        // bounce: D element (m = w = wm*32+mi*16+g*4+r, n = rr = ni*16+m16)
        #pragma unroll
        for (int ni = 0; ni < 4; ++ni)
            #pragma unroll
            for (int mi = 0; mi < 2; ++mi) {
                int rr = ni * 16 + m16;
                int wu = wm * 32 + mi * 16 + g * 4;       // ushort col (w)
                uint2 d;
                d.x = pkbf(acc[mi][ni][0], acc[mi][ni][1]);
                d.y = pkbf(acc[mi][ni][2], acc[mi][ni][3]);
                int u = wu >> 3;
                *(uint2*)(Bs + rr * 64 + ((u ^ SIG(rr)) << 2) + ((wu >> 1) & 3)) = d;
            }
        __syncthreads();

        // read-out + coalesced store (256B runs); kp = 128 + ns*64 + rr
        #pragma unroll
        for (int i = 0; i < 4; ++i) {
            int n = tid + i * 256;                 // 0..1023
            int rr = n >> 4, wsg = n & 15;
            uint4 v = *(const uint4*)(Bs + rr * 64 + ((wsg ^ SIG(rr)) << 2));
            int kp = 128 + ns * 64 + rr;
            int k = kp >> 7, p = kp & 127;
            *(uint4*)(t1 + ((size_t)((bl * LEN + p) * KC + k * NC + c)) * LEN + wsg * 8) = v;
        }
    }
}

// ---------------- k2: per (p, bl) block (1 p-slice, 32KB LDS, 5 blocks/CU)
// Ts rows kc 0..15 (k=0, T_0=I) staged DIRECTLY from x; rows 16..79 from t1.
// stage2: s[w][lu] = Ts[w][kc] x coefF (K=96, padded); stage3: out[u][q] =
// A3[u][lw] x cheb2F, ks 4..19 (l=0 identity added in epilogue). (r14 verbatim)
__global__ __launch_bounds__(256, 5) void k2_mfma(const ushort16* __restrict__ t1,
                                                  const float* __restrict__ x,
                                                  const ushort16* __restrict__ coefF,
                                                  const ushort16* __restrict__ cheb2F,
                                                  float* __restrict__ out, int b0) {
    __shared__ __align__(16) uint32 sm[128 * 64];   // 32KB: Ts [w][kc units swz]; A3 (16x648 ush) aliases
    const int p = blockIdx.x, bl = blockIdx.y, b = b0 + bl;
    const int tid = threadIdx.x;
    const int lane = tid & 63, wave = tid >> 6;
    const int n16 = lane & 15, g = lane >> 4;

    // issue t1 global loads FIRST (kc rows 16..79 -> pair cols a2 = 8..39)
    const uint32* t1u = (const uint32*)(t1 + (size_t)(bl * LEN + p) * (KC * LEN));
    uint4 Av[2], Bv[2];
    #pragma unroll
    for (int i = 0; i < 2; ++i) {
        int it = tid + i * 256;              // 0..511, all active
        int a2 = 8 + (it >> 4), wq = it & 15;
        const uint32* src = t1u + a2 * 128 + wq * 4;
        Av[i] = *(const uint4*)(src);
        Bv[i] = *(const uint4*)(src + 64);
    }
    // k=0 rows from x: pair j = tid>>5 (c = 2j, 2j+1), w0 = (tid&31)*4
    float4 X0, X1;
    {
        int j = tid >> 5, w0 = (tid & 31) << 2;
        const float* xb = x + ((size_t)(b * NC) * LEN + p) * LEN;
        const float* xa = xb + (size_t)(2 * j) * (LEN * LEN);
        X0 = *(const float4*)(xa + w0);
        X1 = *(const float4*)(xa + LEN * LEN + w0);
    }
    // zero K-pad (dw 40..47 = units 10,11) while loads are in flight
    #pragma unroll
    for (int i = 0; i < 4; ++i) {
        int idx = tid + i * 256;             // 0..1023
        int row = idx >> 3, d = idx & 7;
        int u = 10 + (d >> 2);
        sm[row * 64 + ((u ^ SIG(row)) << 2) + (d & 3)] = 0;
    }
    // write k=0 dword-cols (a2 = j = 0..7): sm[w][col j] = pk(x[2j][p][w], x[2j+1][p][w])
    {
        int j = tid >> 5, w0 = (tid & 31) << 2;
        const float* f0 = (const float*)&X0;
        const float* f1 = (const float*)&X1;
        int u0 = j >> 2, lo = j & 3;
        #pragma unroll
        for (int r = 0; r < 4; ++r) {
            int row = w0 + r;
            sm[row * 64 + ((u0 ^ SIG(row)) << 2) + lo] = pkbf(f0[r], f1[r]);
        }
    }
    // transpose t1 kc-pairs into swizzled rows (verified shift/mask merges)
    #pragma unroll
    for (int i = 0; i < 2; ++i) {
        int it = tid + i * 256;
        int a2 = 8 + (it >> 4), wq = it & 15;
        const uint32* av = (const uint32*)&Av[i];
        const uint32* bv = (const uint32*)&Bv[i];
        int u = a2 >> 2, lo = a2 & 3;
        #pragma unroll
        for (int j = 0; j < 4; ++j) {
            int r0 = wq * 8 + 2 * j, r1 = r0 + 1;
            sm[r0 * 64 + ((u ^ SIG(r0)) << 2) + lo] = (av[j] & 0xffffu) | (bv[j] << 16);
            sm[r1 * 64 + ((u ^ SIG(r1)) << 2) + lo] = (av[j] >> 16) | (bv[j] & 0xffff0000u);
        }
    }
    __syncthreads();

    // ---- stage2: rows w = wave*32 + mi*16 + n16
    f32x4 acc[2][5];
    #pragma unroll
    for (int mi = 0; mi < 2; ++mi)
        #pragma unroll
        for (int ni = 0; ni < 5; ++ni) acc[mi][ni] = (f32x4)0.f;

    #pragma unroll
    for (int ks = 0; ks < 3; ++ks) {
        bf16x8 Af[2], Bf[5];
        #pragma unroll
        for (int mi = 0; mi < 2; ++mi) {
            int row = wave * 32 + mi * 16 + n16;
            Af[mi] = frag16(sm + row * 64 + (((ks * 4 + g) ^ SIG(row)) << 2));
        }
        #pragma unroll
        for (int ni = 0; ni < 5; ++ni)
            Bf[ni] = frag16(coefF + ((size_t)(ni * 3 + ks) * 64 + lane) * 8);
        #pragma unroll
        for (int mi = 0; mi < 2; ++mi)
            #pragma unroll
            for (int ni = 0; ni < 5; ++ni)
                acc[mi][ni] = MFMA(Af[mi], Bf[ni], acc[mi][ni]);
    }
    __syncthreads();   // Ts reads done; A3 may overwrite

    // s -> A3: row u = n16 (16 rows, stride 648 ushort), col l*128+w
    {
        ushort16* A3 = (ushort16*)sm;
        #pragma unroll
        for (int mi = 0; mi < 2; ++mi)
            #pragma unroll
            for (int ni = 0; ni < 5; ++ni) {
                int wcol = wave * 32 + mi * 16 + g * 4;
                uint2 d;
                d.x = pkbf(acc[mi][ni][0], acc[mi][ni][1]);
                d.y = pkbf(acc[mi][ni][2], acc[mi][ni][3]);
                *(uint2*)(A3 + n16 * 648 + ni * 128 + wcol) = d;
            }
    }
    __syncthreads();

    // ---- stage3: M=16 (u), wave owns 32 q. Skip l=0 (identity): ks 4..19 only.
    const ushort16* A3r = (const ushort16*)sm;
    f32x4 c3[2];
    c3[0] = (f32x4)0.f; c3[1] = (f32x4)0.f;
    #pragma unroll 4
    for (int ks = 4; ks < 20; ++ks) {
        bf16x8 Aa = frag16(A3r + n16 * 648 + ks * 32 + g * 8);
        #pragma unroll
        for (int nt = 0; nt < 2; ++nt) {
            bf16x8 Bb = frag16(cheb2F + ((size_t)((wave * 2 + nt) * 20 + ks) * 64 + lane) * 8);
            c3[nt] = MFMA(Aa, Bb, c3[nt]);
        }
    }

    #pragma unroll
    for (int nt = 0; nt < 2; ++nt)
        #pragma unroll
        for (int r = 0; r < 4; ++r) {
            int u = g * 4 + r;
            int q = wave * 32 + nt * 16 + n16;
            // l=0 identity contribution: + s[u][w=q] (bf16 in A3 col q)
            uint32 bf = ((uint32)A3r[u * 648 + q]) << 16;
            float l0 = __uint_as_float(bf);
            out[(((size_t)(b * NU + u)) * LEN + p) * LEN + q] = c3[nt][r] + l0;
        }
}

extern "C" void kernel_launch(void* const* d_in, const int* in_sizes, int n_in,
                              void* d_out, int out_size, void* d_ws, size_t ws_size,
                              hipStream_t stream) {
    const float* x     = (const float*)d_in[0];
    const float* coefs = (const float*)d_in[1];
    const float* cheb1 = (const float*)d_in[2];
    const float* cheb2 = (const float*)d_in[3];
    float* out = (float*)d_out;

    const size_t aux_bytes = 163840 + 163840 + 15360;          // cheb1F + cheb2F + coefF
    size_t off = (ws_size - aux_bytes) & ~(size_t)255;
    ushort16* cheb1F = (ushort16*)((char*)d_ws + off);
    ushort16* cheb2F = cheb1F + 81920;
    ushort16* coefF  = cheb2F + 81920;
    ushort16* t1 = (ushort16*)d_ws;

    const size_t per_b = (size_t)LEN * KC * LEN * sizeof(ushort16);        // 2.62 MB
    int chunk = (int)(off / per_b);
    if (chunk < 1) chunk = 1;
    if (chunk > NB) chunk = NB;

    hipLaunchKernelGGL(kconst, dim3(670), dim3(256), 0, stream,
                       coefs, cheb1, cheb2, cheb1F, cheb2F, coefF);
    for (int b0 = 0; b0 < NB; b0 += chunk) {
        int cb = (NB - b0 < chunk) ? (NB - b0) : chunk;
        hipLaunchKernelGGL(kfuse, dim3(NC, cb), dim3(256), 0, stream,
                           x, cheb1F, t1, b0);
        hipLaunchKernelGGL(k2_mfma, dim3(LEN, cb), dim3(256), 0, stream,
                           t1, x, coefF, cheb2F, out, b0);
    }
}